// Round 11
// baseline (116.567 us; speedup 1.0000x reference)
//
#include <hip/hip_runtime.h>
#include <stdint.h>

#define REG_P   0.05f
#define LOG2E   1.4426950408889634f
#define LN2     0.6931471805599453f
#define NSPLIT  16

typedef int   int32x8 __attribute__((ext_vector_type(8)));
typedef float floatx4 __attribute__((ext_vector_type(4)));

__device__ inline int32x8 load32B(const void* p) {
    union { int32x8 v; uint4 q[2]; } u;
    u.q[0] = ((const uint4*)p)[0];
    u.q[1] = ((const uint4*)p)[1];
    return u.v;
}

// block-wide sum of v[0..M): float4 grid-stride + wave butterfly + LDS.
// All 256 threads return the exact total. Uses redbuf[4]; one internal barrier.
__device__ inline float block_sum_f(const float* __restrict__ v, int M, int tid,
                                    float* redbuf) {
    float s = 0.f;
    const float4* v4 = (const float4*)v;
    for (int j = tid; j < (M >> 2); j += 256) {
        float4 q = v4[j];
        s += (q.x + q.y) + (q.z + q.w);
    }
    #pragma unroll
    for (int mask = 1; mask < 64; mask <<= 1) s += __shfl_xor(s, mask, 64);
    int wv = tid >> 6, lane = tid & 63;
    if (lane == 0) redbuf[wv] = s;
    __syncthreads();
    return (redbuf[0] + redbuf[1]) + (redbuf[2] + redbuf[3]);
}

// load 32 consecutive fp32, scale by a2, pack to 32 fp8 e4m3 bytes.
__device__ inline int32x8 pack_a_frag(const float* __restrict__ p, float a2) {
    int32x8 out;
    #pragma unroll
    for (int i = 0; i < 8; ++i) {
        float4 f = ((const float4*)p)[i];
        int w = 0;
        w = __builtin_amdgcn_cvt_pk_fp8_f32(f.x * a2, f.y * a2, w, false);
        w = __builtin_amdgcn_cvt_pk_fp8_f32(f.z * a2, f.w * a2, w, true);
        out[i] = w;
    }
    return out;
}

// k1: T-ONLY pack fp32 -> fp8 e4m3 + per-row ty2. 256 thr = 16 rows x 16 chunks.
// Fragment-ordered Tbs8: tile t (64 cols), chunk (ct,quad,l16) at
//   t*8192 + (ct*64 + quad*16 + l16)*32 holds T[t*64+ct*16+l16][quad*32..+31].
// Block 0 zero-inits d_out (k4 accumulates; stream order guarantees visibility).
__global__ void k1_pack(const float* __restrict__ tgt,
                        unsigned char* __restrict__ Tbs8,
                        float* __restrict__ ty2, float* __restrict__ out, int M) {
    int tid = threadIdx.x;
    if (blockIdx.x == 0 && tid == 0) out[0] = 0.0f;
    int r16 = tid >> 4;
    int c8  = tid & 15;
    int row = blockIdx.x * 16 + r16;
    const float4* sp = (const float4*)(tgt + (size_t)row * 128 + c8 * 8);
    float4 f0 = sp[0], f1 = sp[1];
    int w0 = 0, w1 = 0;
    w0 = __builtin_amdgcn_cvt_pk_fp8_f32(f0.x, f0.y, w0, false);
    w0 = __builtin_amdgcn_cvt_pk_fp8_f32(f0.z, f0.w, w0, true);
    w1 = __builtin_amdgcn_cvt_pk_fp8_f32(f1.x, f1.y, w1, false);
    w1 = __builtin_amdgcn_cvt_pk_fp8_f32(f1.z, f1.w, w1, true);
    uint2 val = make_uint2((unsigned)w0, (unsigned)w1);
    float sq = f0.x*f0.x + f0.y*f0.y + f0.z*f0.z + f0.w*f0.w
             + f1.x*f1.x + f1.y*f1.y + f1.z*f1.z + f1.w*f1.w;
    #pragma unroll
    for (int mask = 1; mask < 16; mask <<= 1) sq += __shfl_xor(sq, mask, 16);
    int t = row >> 6, jc = row & 63;
    int ct = jc >> 4, l16 = jc & 15;
    int quad = c8 >> 2, rem = c8 & 3;
    size_t dst = (size_t)t * 8192 + (size_t)((ct * 64 + quad * 16 + l16) * 32 + rem * 8);
    ((uint2*)(Tbs8 + dst))[0] = val;
    if (c8 == 0) ty2[row] = sq;
}

// k3: l_i = sum_j exp2(b2_j + a2*dot_ij) via MX-fp8 MFMA (16x16x128, scales=1.0).
// a2 folded into A (fp32 src load -> scale -> fp8 pack, in-register, one-time);
// b2_j folded into MFMA C-init (C/D col = l16: {bv} broadcast exact).
// Epilogue = exp2 + add ONLY. No max shift: exponent in [-92,+33], fp32-safe.
// Block = 4 waves x 64 rows = 256 rows; NSPLIT=16 -> split = 512 cols = 32 chunks.
// Grid 1024 = 4 blocks/CU = 4 waves/SIMD (TLP) AND 64 rows/wave (B-reuse):
// per-XCD L2 B-traffic ~33 MB ~ 7.8 us. Barrier-free K loop, rotation prefetch
// (distance 2, <=4KB OOB into ws slack), lag-1 exp2 epilogue.
__global__ __launch_bounds__(256, 4) void k3_main(
    const float* __restrict__ src, const unsigned char* __restrict__ Tbs8,
    const float* __restrict__ psi, const float* __restrict__ ty2,
    float* __restrict__ lpart, int N, int M) {
    __shared__ float sb2a[512];
    __shared__ float redA[4];
    const int tid  = threadIdx.x;
    const int lane = tid & 63;
    const int wv   = tid >> 6;
    const int quad = lane >> 4, l16 = lane & 15;
    const int b = blockIdx.x;
    const int split = b & 15;
    const int i0 = (b >> 4) * 256;
    const int mspan = M / NSPLIT;            // 512
    const int jstart = split * mspan;

    float ty2sum = block_sum_f(ty2, M, tid, redA);   // includes one barrier
    float scale = ty2sum / (float)M;
    float c1 = 1.0f / (REG_P * scale);
    float a2 = 2.0f * LOG2E / (REG_P * scale);

    for (int idx = tid; idx < mspan; idx += 256) {
        int j = jstart + idx;
        sb2a[idx] = (psi[j] * (1.0f / REG_P) - ty2[j] * c1) * LOG2E;
    }
    __syncthreads();                          // last barrier

    // A fragments: rows i0 + wv*64 + rt*16 + l16, k [quad*32, +32), x a2, fp8
    int32x8 afrag[4];
    #pragma unroll
    for (int rt = 0; rt < 4; ++rt)
        afrag[rt] = pack_a_frag(
            src + (size_t)(i0 + wv * 64 + rt * 16 + l16) * 128 + quad * 32, a2);

    float ls[4][4];
    #pragma unroll
    for (int rt = 0; rt < 4; ++rt)
        #pragma unroll
        for (int r = 0; r < 4; ++r) ls[rt][r] = 0.0f;

    const unsigned char* gb = Tbs8 + (size_t)jstart * 128 + (size_t)lane * 32;
    const int SC = 0x7F7F7F7F;               // E8M0 1.0 in every byte

    int32x8 bc = load32B(gb);                // chunk 0
    int32x8 bn = load32B(gb + 2048);         // chunk 1
    floatx4 accP[4];
    bool first = true;

    #pragma unroll 4
    for (int u = 0; u < 32; ++u) {
        float bv = sb2a[u * 16 + l16];
        floatx4 bv4 = (floatx4){bv, bv, bv, bv};
        floatx4 a[4];
        #pragma unroll
        for (int rt = 0; rt < 4; ++rt)
            a[rt] = __builtin_amdgcn_mfma_scale_f32_16x16x128_f8f6f4(
                afrag[rt], bc, bv4, 0, 0, 0, SC, 0, SC);
        int32x8 bf = load32B(gb + (size_t)(u + 2) * 2048);  // <=4KB OOB, never used
        if (!first) {
            #pragma unroll
            for (int rt = 0; rt < 4; ++rt)
                #pragma unroll
                for (int r = 0; r < 4; ++r)
                    ls[rt][r] += __builtin_amdgcn_exp2f(accP[rt][r]);
        }
        #pragma unroll
        for (int rt = 0; rt < 4; ++rt) accP[rt] = a[rt];
        bc = bn; bn = bf;
        first = false;
    }
    #pragma unroll
    for (int rt = 0; rt < 4; ++rt)
        #pragma unroll
        for (int r = 0; r < 4; ++r)
            ls[rt][r] += __builtin_amdgcn_exp2f(accP[rt][r]);

    // sum over the 16 lanes (l16) sharing each row
    #pragma unroll
    for (int rt = 0; rt < 4; ++rt)
        #pragma unroll
        for (int r = 0; r < 4; ++r) {
            float v = ls[rt][r];
            #pragma unroll
            for (int mask = 1; mask < 16; mask <<= 1) v += __shfl_xor(v, mask, 64);
            if (l16 == 0) {
                int rowg = i0 + wv * 64 + rt * 16 + quad * 4 + r;
                lpart[(size_t)rowg * NSPLIT + split] = v;
            }
        }
}

// k4: one row per thread (grid N/256). Self-computes scale. Per-row term:
//   -REG*LN2*log2(sum_p lpart)/N, + psi[i]/M for i<M, + per-thread partial of
//   sum(src^2)/(N*scale) (block-strided slice; mean sx2 needs no per-row values).
// Block reduce -> one atomicAdd into d_out. Block 0 adds REG*ln(M).
__global__ void k4_reduce(const float* __restrict__ lpart,
                          const float* __restrict__ src,
                          const float* __restrict__ psi,
                          const float* __restrict__ ty2,
                          float* __restrict__ out, int N, int M) {
    __shared__ float redA[4];
    __shared__ float redB[4];
    int tid = threadIdx.x;
    float ty2s = block_sum_f(ty2, M, tid, redA);
    float scale = ty2s / (float)M;

    int i = blockIdx.x * 256 + tid;
    const float4* lp = (const float4*)(lpart + (size_t)i * NSPLIT);
    float s = 0.f;
    #pragma unroll
    for (int q = 0; q < NSPLIT / 4; ++q) {
        float4 p = lp[q];
        s += (p.x + p.y) + (p.z + p.w);
    }
    float L2 = __builtin_amdgcn_logf(s);     // v_log_f32 = log2
    float t = -REG_P * LN2 * L2 * (1.0f / (float)N);
    if (i < M) t += psi[i] * (1.0f / (float)M);

    // src^2 partial: this block's slice of N*128 floats
    {
        const float4* s4 = (const float4*)src;
        int per_block = (N * 128 / 4) / gridDim.x;          // 8192 float4
        int base = blockIdx.x * per_block;
        float s2 = 0.f;
        for (int j = base + tid; j < base + per_block; j += 256) {
            float4 q = s4[j];
            s2 += (q.x*q.x + q.y*q.y) + (q.z*q.z + q.w*q.w);
        }
        t += s2 / ((float)N * scale);
    }

    #pragma unroll
    for (int mask = 1; mask < 64; mask <<= 1) t += __shfl_xor(t, mask, 64);
    int wv = tid >> 6, lane = tid & 63;
    if (lane == 0) redB[wv] = t;
    __syncthreads();
    if (tid == 0) {
        float total = (redB[0] + redB[1]) + (redB[2] + redB[3]);
        if (blockIdx.x == 0) total += REG_P * logf((float)M);
        atomicAdd(out, total);
    }
}

extern "C" void kernel_launch(void* const* d_in, const int* in_sizes, int n_in,
                              void* d_out, int out_size, void* d_ws, size_t ws_size,
                              hipStream_t stream) {
    const float* src = (const float*)d_in[0];
    const float* tgt = (const float*)d_in[1];
    const float* psi = (const float*)d_in[2];
    const int D = 128;
    const int N = in_sizes[0] / D;   // 16384
    const int M = in_sizes[1] / D;   // 8192

    char* ws = (char*)d_ws;
    float* ty2   = (float*)ws;                                   // M floats
    float* lpart = (float*)(ws + (size_t)M * 4);                 // N*16 floats
    size_t off = (size_t)M * 4 + (size_t)N * NSPLIT * 4;
    off = (off + 255) & ~(size_t)255;
    unsigned char* Tbs8 = (unsigned char*)(ws + off);            // 1 MB + slack after

    k1_pack<<<M / 16, 256, 0, stream>>>(tgt, Tbs8, ty2, (float*)d_out, M);
    k3_main<<<(N / 256) * NSPLIT, 256, 0, stream>>>(src, Tbs8, psi, ty2, lpart, N, M);
    k4_reduce<<<N / 256, 256, 0, stream>>>(lpart, src, psi, ty2, (float*)d_out, N, M);
}

// Round 12
// 97.658 us; speedup vs baseline: 1.1936x; 1.1936x over previous
//
#include <hip/hip_runtime.h>
#include <stdint.h>

#define REG_P   0.05f
#define LOG2E   1.4426950408889634f
#define LN2     0.6931471805599453f
#define NSPLIT  16

typedef int   int32x8 __attribute__((ext_vector_type(8)));
typedef float floatx4 __attribute__((ext_vector_type(4)));

__device__ inline int32x8 load32B(const void* p) {
    union { int32x8 v; uint4 q[2]; } u;
    u.q[0] = ((const uint4*)p)[0];
    u.q[1] = ((const uint4*)p)[1];
    return u.v;
}

// block-wide sum of v[0..M): float4 grid-stride + wave butterfly + LDS.
// All 256 threads return the exact total. Uses redbuf[4]; one internal barrier.
__device__ inline float block_sum_f(const float* __restrict__ v, int M, int tid,
                                    float* redbuf) {
    float s = 0.f;
    const float4* v4 = (const float4*)v;
    for (int j = tid; j < (M >> 2); j += 256) {
        float4 q = v4[j];
        s += (q.x + q.y) + (q.z + q.w);
    }
    #pragma unroll
    for (int mask = 1; mask < 64; mask <<= 1) s += __shfl_xor(s, mask, 64);
    int wv = tid >> 6, lane = tid & 63;
    if (lane == 0) redbuf[wv] = s;
    __syncthreads();
    return (redbuf[0] + redbuf[1]) + (redbuf[2] + redbuf[3]);
}

// k1: pack fp32 -> fp8 e4m3 (hw cvt) + per-row fp32 squared norms.
// 256 thr = 16 rows x 16 chunks of 8 values. S -> row-major Sb8 (128 B/row,
// one-time 2 MB: avoids R11's 16x re-read of 8 MB fp32 src in k3).
// T -> fragment-ordered Tbs8: tile t (64 cols), chunk (ct,quad,l16) at
//   t*8192 + (ct*64 + quad*16 + l16)*32 holds T[t*64+ct*16+l16][quad*32..+31].
// Block 0 zero-inits d_out (k4 accumulates; stream order guarantees visibility).
__global__ void k1_pack(const float* __restrict__ src, const float* __restrict__ tgt,
                        unsigned char* __restrict__ Sb8, unsigned char* __restrict__ Tbs8,
                        float* __restrict__ sx2, float* __restrict__ ty2,
                        float* __restrict__ out, int N, int M) {
    int tid = threadIdx.x;
    if (blockIdx.x == 0 && tid == 0) out[0] = 0.0f;
    int r16 = tid >> 4;
    int c8  = tid & 15;
    int row_id = blockIdx.x * 16 + r16;
    bool isS = row_id < N;
    int row = isS ? row_id : row_id - N;
    const float4* sp = (const float4*)((isS ? src : tgt) + (size_t)row * 128 + c8 * 8);
    float4 f0 = sp[0], f1 = sp[1];
    int w0 = 0, w1 = 0;
    w0 = __builtin_amdgcn_cvt_pk_fp8_f32(f0.x, f0.y, w0, false);
    w0 = __builtin_amdgcn_cvt_pk_fp8_f32(f0.z, f0.w, w0, true);
    w1 = __builtin_amdgcn_cvt_pk_fp8_f32(f1.x, f1.y, w1, false);
    w1 = __builtin_amdgcn_cvt_pk_fp8_f32(f1.z, f1.w, w1, true);
    uint2 val = make_uint2((unsigned)w0, (unsigned)w1);
    float sq = f0.x*f0.x + f0.y*f0.y + f0.z*f0.z + f0.w*f0.w
             + f1.x*f1.x + f1.y*f1.y + f1.z*f1.z + f1.w*f1.w;
    #pragma unroll
    for (int mask = 1; mask < 16; mask <<= 1) sq += __shfl_xor(sq, mask, 16);
    if (isS) {
        ((uint2*)(Sb8 + (size_t)row * 128 + c8 * 8))[0] = val;
        if (c8 == 0) sx2[row] = sq;
    } else {
        int t = row >> 6, jc = row & 63;
        int ct = jc >> 4, l16 = jc & 15;
        int quad = c8 >> 2, rem = c8 & 3;
        size_t dst = (size_t)t * 8192 + (size_t)((ct * 64 + quad * 16 + l16) * 32 + rem * 8);
        ((uint2*)(Tbs8 + dst))[0] = val;
        if (c8 == 0) ty2[row] = sq;
    }
}

// k3: l_i = sum_j exp2(b2_j + a2*dot_ij) via MX-fp8 MFMA (16x16x128, scales=1.0).
// No max shift: exponent in [-92,+33], fp32-safe.
// Block = 4 waves x 64 rows = 256 rows; NSPLIT=16 -> split = 512 cols = 32 chunks.
// Grid 1024 = 4 blocks/CU = 4 waves/SIMD (TLP) AND 64 rows/wave (B-reuse):
// per-XCD L2 B-traffic ~32 MB ~ 7.5 us; trans floor 13.7 us is the wall.
// A pre-packed fp8 (Sb8, 2 MB), a2 via lag-1 epilogue fma (1.7 us — cheap).
// Barrier-free K loop, rotation prefetch (distance 2, <=4KB OOB into ws slack).
__global__ __launch_bounds__(256, 4) void k3_main(
    const unsigned char* __restrict__ Sb8, const unsigned char* __restrict__ Tbs8,
    const float* __restrict__ psi, const float* __restrict__ ty2,
    float* __restrict__ lpart, int N, int M) {
    __shared__ float sb2a[512];
    __shared__ float redA[4];
    const int tid  = threadIdx.x;
    const int lane = tid & 63;
    const int wv   = tid >> 6;
    const int quad = lane >> 4, l16 = lane & 15;
    const int b = blockIdx.x;
    const int split = b & 15;
    const int i0 = (b >> 4) * 256;
    const int mspan = M / NSPLIT;            // 512
    const int jstart = split * mspan;

    float ty2sum = block_sum_f(ty2, M, tid, redA);   // includes one barrier
    float scale = ty2sum / (float)M;
    float c1 = 1.0f / (REG_P * scale);
    float a2 = 2.0f * LOG2E / (REG_P * scale);

    for (int idx = tid; idx < mspan; idx += 256) {
        int j = jstart + idx;
        sb2a[idx] = (psi[j] * (1.0f / REG_P) - ty2[j] * c1) * LOG2E;
    }
    __syncthreads();                          // last barrier

    // A fragments: rows i0 + wv*64 + rt*16 + l16, k-bytes [quad*32, +32)
    int32x8 afrag[4];
    #pragma unroll
    for (int rt = 0; rt < 4; ++rt)
        afrag[rt] = load32B(Sb8 + (size_t)(i0 + wv * 64 + rt * 16 + l16) * 128 + quad * 32);

    float ls[4][4];
    #pragma unroll
    for (int rt = 0; rt < 4; ++rt)
        #pragma unroll
        for (int r = 0; r < 4; ++r) ls[rt][r] = 0.0f;

    const unsigned char* gb = Tbs8 + (size_t)jstart * 128 + (size_t)lane * 32;
    const floatx4 zero4 = (floatx4){0.f, 0.f, 0.f, 0.f};
    const int SC = 0x7F7F7F7F;               // E8M0 1.0 in every byte

    int32x8 bc = load32B(gb);                // chunk 0
    int32x8 bn = load32B(gb + 2048);         // chunk 1
    floatx4 accP[4];
    float bvP = 0.0f;
    bool first = true;

    #pragma unroll 4
    for (int u = 0; u < 32; ++u) {
        float bv = sb2a[u * 16 + l16];
        floatx4 a[4];
        #pragma unroll
        for (int rt = 0; rt < 4; ++rt)
            a[rt] = __builtin_amdgcn_mfma_scale_f32_16x16x128_f8f6f4(
                afrag[rt], bc, zero4, 0, 0, 0, SC, 0, SC);
        int32x8 bf = load32B(gb + (size_t)(u + 2) * 2048);  // <=4KB OOB, never used
        if (!first) {                        // lag-1 epilogue
            #pragma unroll
            for (int rt = 0; rt < 4; ++rt)
                #pragma unroll
                for (int r = 0; r < 4; ++r)
                    ls[rt][r] += __builtin_amdgcn_exp2f(fmaf(a2, accP[rt][r], bvP));
        }
        #pragma unroll
        for (int rt = 0; rt < 4; ++rt) accP[rt] = a[rt];
        bvP = bv;
        bc = bn; bn = bf;
        first = false;
    }
    #pragma unroll
    for (int rt = 0; rt < 4; ++rt)
        #pragma unroll
        for (int r = 0; r < 4; ++r)
            ls[rt][r] += __builtin_amdgcn_exp2f(fmaf(a2, accP[rt][r], bvP));

    // sum over the 16 lanes (l16) sharing each row
    #pragma unroll
    for (int rt = 0; rt < 4; ++rt)
        #pragma unroll
        for (int r = 0; r < 4; ++r) {
            float v = ls[rt][r];
            #pragma unroll
            for (int mask = 1; mask < 16; mask <<= 1) v += __shfl_xor(v, mask, 64);
            if (l16 == 0) {
                int rowg = i0 + wv * 64 + rt * 16 + quad * 4 + r;
                lpart[(size_t)rowg * NSPLIT + split] = v;
            }
        }
}

// k4: one row per thread. Self-computes scale. Per-row term:
//   (-REG*LN2*log2(sum_p lpart) + sx2[i]/scale)/N, + psi[i]/M for i<M.
// Block reduce -> one atomicAdd into d_out. Block 0 adds REG*ln(M).
__global__ void k4_reduce(const float* __restrict__ lpart,
                          const float* __restrict__ sx2,
                          const float* __restrict__ psi,
                          const float* __restrict__ ty2,
                          float* __restrict__ out, int N, int M) {
    __shared__ float redA[4];
    __shared__ float redB[4];
    int tid = threadIdx.x;
    float ty2s = block_sum_f(ty2, M, tid, redA);
    float scale = ty2s / (float)M;

    int i = blockIdx.x * 256 + tid;
    const float4* lp = (const float4*)(lpart + (size_t)i * NSPLIT);
    float s = 0.f;
    #pragma unroll
    for (int q = 0; q < NSPLIT / 4; ++q) {
        float4 p = lp[q];
        s += (p.x + p.y) + (p.z + p.w);
    }
    float L2 = __builtin_amdgcn_logf(s);     // v_log_f32 = log2
    float t = (-REG_P * LN2 * L2 + sx2[i] / scale) * (1.0f / (float)N);
    if (i < M) t += psi[i] * (1.0f / (float)M);
    #pragma unroll
    for (int mask = 1; mask < 64; mask <<= 1) t += __shfl_xor(t, mask, 64);
    int wv = tid >> 6, lane = tid & 63;
    if (lane == 0) redB[wv] = t;
    __syncthreads();
    if (tid == 0) {
        float total = (redB[0] + redB[1]) + (redB[2] + redB[3]);
        if (blockIdx.x == 0) total += REG_P * logf((float)M);
        atomicAdd(out, total);
    }
}

extern "C" void kernel_launch(void* const* d_in, const int* in_sizes, int n_in,
                              void* d_out, int out_size, void* d_ws, size_t ws_size,
                              hipStream_t stream) {
    const float* src = (const float*)d_in[0];
    const float* tgt = (const float*)d_in[1];
    const float* psi = (const float*)d_in[2];
    const int D = 128;
    const int N = in_sizes[0] / D;   // 16384
    const int M = in_sizes[1] / D;   // 8192

    char* ws = (char*)d_ws;
    float* sx2   = (float*)ws;                                   // N floats
    float* ty2   = (float*)(ws + (size_t)N * 4);                 // M floats
    float* lpart = (float*)(ws + (size_t)N * 4 + (size_t)M * 4); // N*16 floats
    size_t off = (size_t)N * 4 + (size_t)M * 4 + (size_t)N * NSPLIT * 4;
    off = (off + 255) & ~(size_t)255;
    unsigned char* Sb8  = (unsigned char*)(ws + off);            // 2 MB
    unsigned char* Tbs8 = Sb8 + (size_t)N * 128;                 // 1 MB + slack after

    k1_pack<<<(N + M) / 16, 256, 0, stream>>>(src, tgt, Sb8, Tbs8, sx2, ty2,
                                              (float*)d_out, N, M);
    k3_main<<<(N / 256) * NSPLIT, 256, 0, stream>>>(Sb8, Tbs8, psi, ty2, lpart, N, M);
    k4_reduce<<<N / 256, 256, 0, stream>>>(lpart, sx2, psi, ty2, (float*)d_out, N, M);
}